// Round 20
// baseline (71.445 us; speedup 1.0000x reference)
//
#include <hip/hip_runtime.h>
#include <hip/hip_bf16.h>

// Shapes (fixed by setup_inputs): B=32, L=2048, V=30522, Dw=300, H=768, S=L/P=128
#define B_   32
#define L_   2048
#define V_   30522
#define DW   300
#define H_   768
#define KP   320              // Dw padded to multiple of 32 for MFMA K
#define NT   (H_/16)          // 48 n-tiles
#define KT   (KP/32)          // 10 k-tiles
#define VPAD 30528            // V rounded up; 30528 = 954 * 32 exactly
#define MB   32               // rows per block (2 m-tiles) -> acc 48 AGPR, 2 blocks/CU
#define NMT  2                // m-tiles per wave
#define NW   6                // n-tiles per wave (8 waves x 6 = 48)
#define APAD 336              // padded LDS row stride (bf16): 672 B rows, 16B-aligned

typedef __attribute__((ext_vector_type(8))) short bf16x8;
typedef __attribute__((ext_vector_type(4))) float f32x4;

// ---------------- K0: fused setup — pack_w | pe_table | sep_scan (blockIdx-ranged) ------------
__global__ void setup(const float* __restrict__ W, __hip_bfloat16* __restrict__ Wp,
                      float* __restrict__ PE, int peBlocks, int S,
                      const int* __restrict__ sep, int* __restrict__ pos,
                      int* __restrict__ nsep) {
    __shared__ int cnt[256];
    int bid = blockIdx.x;
    if (bid < 120) {                                   // ---- pack_w: 120*256 = NT*KT*64
        int t = bid * 256 + threadIdx.x;
        int lane = t & 63;
        int f    = t >> 6;
        int n    = f % NT;
        int kt   = f / NT;
        int col  = n * 16 + (lane & 15);
        int k0   = kt * 32 + (lane >> 4) * 8;
        union { __hip_bfloat16 h[8]; int4 v; } u;
        #pragma unroll
        for (int j = 0; j < 8; ++j) {
            int k = k0 + j;
            float w = (k < DW) ? W[(size_t)k * H_ + col] : 0.f;
            u.h[j] = __float2bfloat16(w);
        }
        reinterpret_cast<int4*>(Wp)[t] = u.v;
    } else if (bid < 120 + peBlocks) {                 // ---- pe_table
        int t = (bid - 120) * 256 + threadIdx.x;
        if (t < S * H_) {
            int s = t / H_, n = t % H_;
            const float cexp = -9.210340371976184f / (float)H_;   // -ln(10000)/H
            float div = expf((float)(2 * (n >> 1)) * cexp);
            float ang = (float)s * div;
            PE[t] = (n & 1) ? cosf(ang) : sinf(ang);
        }
    } else {                                           // ---- sep_scan: one block per batch row
        int b = bid - 120 - peBlocks;
        const int* row = sep + (size_t)b * L_;
        int tid = threadIdx.x;
        int local[8]; int c = 0;
        #pragma unroll
        for (int i = 0; i < 8; ++i) { int v = row[tid * 8 + i]; local[i] = v; c += v; }
        cnt[tid] = c; __syncthreads();
        for (int ofs = 1; ofs < 256; ofs <<= 1) {      // Hillis-Steele inclusive scan
            int v = (tid >= ofs) ? cnt[tid - ofs] : 0;
            __syncthreads();
            cnt[tid] += v;
            __syncthreads();
        }
        int w = cnt[tid] - c;                          // exclusive prefix
        #pragma unroll
        for (int i = 0; i < 8; ++i)
            if (local[i]) { pos[(size_t)b * L_ + w] = tid * 8 + i; ++w; }
        if (tid == 255) nsep[b] = cnt[255];
    }
}

// ---------------- K1: G[v] = LN2(relu(LN1(emb[v]) @ W + b)) — coalesced-raw LN1 staging -------
// r20 staging rework: phase A block-loads the 32x300 f32 emb tile (contiguous, 2400 float4,
// 16B/lane coalesced) into sRaw; phase B computes LN1 per row from LDS (2 float4 reads/row
// vs 5 HBM dwords) and writes bf16 sA. Rows >= V get zero raw -> finite never-gathered G.
// K-loop/epilogue identical to r16 best (49.6 us). LDS 62 KB -> still 2 blocks/CU.
// C/D layout (m89-verified): col = lane&15, row = (lane>>4)*4 + reg.
__global__ void __launch_bounds__(512, 4)
gemm_ln2(const float* __restrict__ emb, const float* __restrict__ g1,
         const float* __restrict__ b1, const __hip_bfloat16* __restrict__ Wp,
         const float* __restrict__ bias, const float* __restrict__ g2,
         const float* __restrict__ b2, __hip_bfloat16* __restrict__ G) {
    __shared__ float sRaw[MB * DW];                    // 38,400 B raw fp32 emb tile
    __shared__ __hip_bfloat16 sA[MB * APAD];           // 21,504 B LN1'd bf16 A tile
    __shared__ float sred[2][8][MB];                   // 2 KB
    int tid  = threadIdx.x;
    int w    = tid >> 6;
    int lane = tid & 63;
    int r = lane & 15, q = lane >> 4;
    size_t row0 = (size_t)blockIdx.x * MB;

    const bf16x8* Bv = reinterpret_cast<const bf16x8*>(Wp) + (size_t)w * NW * 64 + lane;
    int phase = (int)(blockIdx.x % KT);

    bf16x8 bbuf[2][NW];

    // prologue: issue B loads for kt=phase FIRST (independent; overlap the staging)
    {
        const bf16x8* bp = Bv + (size_t)phase * NT * 64;
        #pragma unroll
        for (int nl = 0; nl < NW; ++nl) bbuf[0][nl] = bp[nl * 64];
    }

    // ---- phase A: block-coalesced raw load, emb[row0..row0+32) -> sRaw (float4) ----
    {
        const float4* esrc = reinterpret_cast<const float4*>(emb + row0 * DW);
        long validf4 = ((long)V_ * DW) / 4 - (long)(row0 * DW) / 4;   // in-range float4s
        int lim = (validf4 > (long)(MB * DW / 4)) ? (MB * DW / 4) : (int)validf4;
        #pragma unroll
        for (int i = 0; i < 5; ++i) {
            int j = tid + i * 512;
            if (j < MB * DW / 4) {                     // 2400 float4 total
                float4 v;
                if (j < lim) v = esrc[j];
                else { v.x = 0.f; v.y = 0.f; v.z = 0.f; v.w = 0.f; }
                *reinterpret_cast<float4*>(&sRaw[j * 4]) = v;
            }
        }
    }
    __syncthreads();                                   // sRaw ready

    // ---- phase B: per-row LN1 from LDS; wave w handles rows w*4..w*4+3 ----
    {
        int k0 = lane << 2;                            // 0..252, always < DW
        int k1 = k0 + 256;                             // 256..508
        bool val1 = (k1 + 3 < DW);                     // lanes 0..10 carry real data
        float4 g1a = *reinterpret_cast<const float4*>(g1 + k0);
        float4 b1a = *reinterpret_cast<const float4*>(b1 + k0);
        float4 g1b, b1b;
        if (val1) {
            g1b = *reinterpret_cast<const float4*>(g1 + k1);
            b1b = *reinterpret_cast<const float4*>(b1 + k1);
        } else { g1b.x=g1b.y=g1b.z=g1b.w=0.f; b1b.x=b1b.y=b1b.z=b1b.w=0.f; }
        #pragma unroll
        for (int rr = 0; rr < 4; ++rr) {
            int lrow = w * 4 + rr;
            const float* rp = &sRaw[(size_t)lrow * DW];
            float4 v0 = *reinterpret_cast<const float4*>(rp + k0);
            float4 v1;
            if (val1) v1 = *reinterpret_cast<const float4*>(rp + k1);
            else { v1.x=0.f; v1.y=0.f; v1.z=0.f; v1.w=0.f; }
            float s  = v0.x + v0.y + v0.z + v0.w + v1.x + v1.y + v1.z + v1.w;
            float ss = v0.x*v0.x + v0.y*v0.y + v0.z*v0.z + v0.w*v0.w
                     + v1.x*v1.x + v1.y*v1.y + v1.z*v1.z + v1.w*v1.w;
            #pragma unroll
            for (int m = 32; m >= 1; m >>= 1) { s += __shfl_xor(s, m); ss += __shfl_xor(ss, m); }
            float mu   = s / (float)DW;
            float var  = ss / (float)DW - mu * mu;
            float rstd = rsqrtf(var + 1e-12f);
            __hip_bfloat16* dst = &sA[lrow * APAD];
            union { __hip_bfloat16 h[4]; uint2 u2; } p0;
            p0.h[0] = __float2bfloat16(g1a.x * ((v0.x - mu) * rstd) + b1a.x);
            p0.h[1] = __float2bfloat16(g1a.y * ((v0.y - mu) * rstd) + b1a.y);
            p0.h[2] = __float2bfloat16(g1a.z * ((v0.z - mu) * rstd) + b1a.z);
            p0.h[3] = __float2bfloat16(g1a.w * ((v0.w - mu) * rstd) + b1a.w);
            *reinterpret_cast<uint2*>(&dst[k0]) = p0.u2;
            if (k1 < KP) {                             // lanes 0..15: data (0-10) or pad zeros
                union { __hip_bfloat16 h[4]; uint2 u2; } p1;
                if (val1) {
                    p1.h[0] = __float2bfloat16(g1b.x * ((v1.x - mu) * rstd) + b1b.x);
                    p1.h[1] = __float2bfloat16(g1b.y * ((v1.y - mu) * rstd) + b1b.y);
                    p1.h[2] = __float2bfloat16(g1b.z * ((v1.z - mu) * rstd) + b1b.z);
                    p1.h[3] = __float2bfloat16(g1b.w * ((v1.w - mu) * rstd) + b1b.w);
                } else { p1.u2.x = 0u; p1.u2.y = 0u; }
                *reinterpret_cast<uint2*>(&dst[k1]) = p1.u2;
            }
        }
    }

    f32x4 acc[NW][NMT];
    #pragma unroll
    for (int nl = 0; nl < NW; ++nl)
        #pragma unroll
        for (int m = 0; m < NMT; ++m) acc[nl][m] = (f32x4){0.f, 0.f, 0.f, 0.f};

    const char* sAc = reinterpret_cast<const char*>(sA);
    const int abase = r * (APAD * 2) + q * 16;         // lane's A byte base (m=0, kt=0)

    __syncthreads();                                   // sA ready

    #pragma unroll                                     // FULL unroll: all buf indices static
    for (int i = 0; i < KT; ++i) {
        const int cur = i & 1, nxt = (i + 1) & 1;
        int kt = phase + i; if (kt >= KT) kt -= KT;
        if (i + 1 < KT) {                              // prefetch kt+1's B (global)
            int ktn = phase + i + 1; if (ktn >= KT) ktn -= KT;
            const bf16x8* bp = Bv + (size_t)ktn * NT * 64;
            #pragma unroll
            for (int nl = 0; nl < NW; ++nl) bbuf[nxt][nl] = bp[nl * 64];
        }
        __builtin_amdgcn_sched_barrier(0);             // prefetch may NOT sink below MFMAs
        // A direct from LDS (compiler emits counted lgkmcnt)
        bf16x8 a0 = *reinterpret_cast<const bf16x8*>(sAc + abase + kt * 64);
        bf16x8 a1 = *reinterpret_cast<const bf16x8*>(sAc + abase + 16 * APAD * 2 + kt * 64);
        __builtin_amdgcn_s_setprio(1);                 // T5: favor MFMA wave
        #pragma unroll
        for (int nl = 0; nl < NW; ++nl) {
            acc[nl][0] = __builtin_amdgcn_mfma_f32_16x16x32_bf16(a0, bbuf[cur][nl], acc[nl][0], 0, 0, 0);
            acc[nl][1] = __builtin_amdgcn_mfma_f32_16x16x32_bf16(a1, bbuf[cur][nl], acc[nl][1], 0, 0, 0);
        }
        __builtin_amdgcn_s_setprio(0);
    }

    // bias + relu + in-wave partial stats (over this wave's 96 cols)
    float s_[NMT][4], ss_[NMT][4];
    #pragma unroll
    for (int m = 0; m < NMT; ++m)
        #pragma unroll
        for (int j = 0; j < 4; ++j) { s_[m][j] = 0.f; ss_[m][j] = 0.f; }
    #pragma unroll
    for (int nl = 0; nl < NW; ++nl) {
        float bn = bias[w * 96 + nl * 16 + r];
        #pragma unroll
        for (int m = 0; m < NMT; ++m)
            #pragma unroll
            for (int j = 0; j < 4; ++j) {
                float v = acc[nl][m][j] + bn;
                v = v > 0.f ? v : 0.f;
                acc[nl][m][j] = v;
                s_[m][j] += v; ss_[m][j] += v * v;
            }
    }
    #pragma unroll
    for (int msk = 1; msk < 16; msk <<= 1)             // reduce across the 16 r-lanes
        #pragma unroll
        for (int m = 0; m < NMT; ++m)
            #pragma unroll
            for (int j = 0; j < 4; ++j) {
                s_[m][j]  += __shfl_xor(s_[m][j],  msk);
                ss_[m][j] += __shfl_xor(ss_[m][j], msk);
            }
    if (r == 0) {                                      // publish wave partials
        #pragma unroll
        for (int m = 0; m < NMT; ++m)
            #pragma unroll
            for (int j = 0; j < 4; ++j) {
                int row = m * 16 + q * 4 + j;
                sred[0][w][row] = s_[m][j];
                sred[1][w][row] = ss_[m][j];
            }
    }
    __syncthreads();

    #pragma unroll
    for (int m = 0; m < NMT; ++m) {
        #pragma unroll
        for (int j = 0; j < 4; ++j) {
            int row = m * 16 + q * 4 + j;
            float ts = 0.f, tss = 0.f;
            #pragma unroll
            for (int ww = 0; ww < 8; ++ww) { ts += sred[0][ww][row]; tss += sred[1][ww][row]; }
            float mu   = ts / (float)H_;
            float var  = tss / (float)H_ - mu * mu;
            float rstd = rsqrtf(var + 1e-12f);
            s_[m][j]  = mu;                            // reuse as mu
            ss_[m][j] = rstd;                          // reuse as rstd
        }
    }
    #pragma unroll
    for (int nl = 0; nl < NW; ++nl) {
        int col = w * 96 + nl * 16 + r;
        float gg = g2[col], bb = b2[col];
        #pragma unroll
        for (int m = 0; m < NMT; ++m)
            #pragma unroll
            for (int j = 0; j < 4; ++j) {
                size_t rowg = row0 + m * 16 + q * 4 + j;
                float val = gg * (acc[nl][m][j] - s_[m][j]) * ss_[m][j] + bb;
                G[rowg * H_ + col] = __float2bfloat16(val);
            }
    }
}

// ---------------- K2: out[b,s,:] = mean_{t in seg(b,s)} G[ids[b,t]] + PE[s] -------------------
// r16's best version: 384 thr = 4 groups x 96 lanes (r17's 768-thr regressed +5.6 us).
__global__ void seg_gather(const int* __restrict__ ids, const int* __restrict__ pos,
                           const int* __restrict__ nsep, const __hip_bfloat16* __restrict__ G,
                           const float* __restrict__ PE, float* __restrict__ out, int S) {
    int blk = blockIdx.x;
    int s = blk % S, b = blk / S;
    int tid = threadIdx.x;
    int g = tid / 96;
    int l = tid % 96;
    int ns = nsep[b];
    int lo, hi;
    if (s > ns) { lo = 1; hi = 0; }                    // empty segment
    else {
        lo = (s == 0) ? 0 : pos[(size_t)b * L_ + (s - 1)] + 1;
        hi = (s < ns) ? pos[(size_t)b * L_ + s] - 1 : L_ - 1;   // s==ns: tail after last sep
    }
    int cnt = hi - lo + 1; if (cnt < 0) cnt = 0;

    float a[8] = {0.f, 0.f, 0.f, 0.f, 0.f, 0.f, 0.f, 0.f};
    for (int t = lo + g; t <= hi; t += 4) {
        int v = ids[(size_t)b * L_ + t];
        int4 raw = *reinterpret_cast<const int4*>(G + (size_t)v * H_ + l * 8);
        const unsigned short* u = reinterpret_cast<const unsigned short*>(&raw);
        #pragma unroll
        for (int k = 0; k < 8; ++k) {
            union { unsigned int i; float f; } c; c.i = ((unsigned int)u[k]) << 16;
            a[k] += c.f;
        }
    }
    __shared__ float red[3][96 * 8];                   // 9 KB
    if (g > 0) {
        #pragma unroll
        for (int k = 0; k < 8; ++k) red[g - 1][l * 8 + k] = a[k];
    }
    __syncthreads();
    if (g == 0) {
        float inv = (cnt > 0) ? 1.f / (float)cnt : 0.f;
        float* orow = out + ((size_t)b * S + s) * H_;
        const float* pe = PE + (size_t)s * H_;
        #pragma unroll
        for (int k = 0; k < 8; ++k) {
            int n = l * 8 + k;
            float tot = a[k] + red[0][l * 8 + k] + red[1][l * 8 + k] + red[2][l * 8 + k];
            orow[n] = tot * inv + pe[n];
        }
    }
}

// ---------------- host launcher ----------------
extern "C" void kernel_launch(void* const* d_in, const int* in_sizes, int n_in,
                              void* d_out, int out_size, void* d_ws, size_t ws_size,
                              hipStream_t stream) {
    const int*   ids  = (const int*)d_in[0];
    const int*   sep  = (const int*)d_in[1];
    const float* emb  = (const float*)d_in[3];
    const float* g1   = (const float*)d_in[4];
    const float* b1   = (const float*)d_in[5];
    const float* W    = (const float*)d_in[6];
    const float* bias = (const float*)d_in[7];
    const float* g2   = (const float*)d_in[8];
    const float* b2   = (const float*)d_in[9];
    float* out = (float*)d_out;

    int S = out_size / (B_ * H_);                      // 128

    // workspace layout (all offsets 16B-aligned)
    char* ws = (char*)d_ws;
    __hip_bfloat16* Wp  = (__hip_bfloat16*)(ws);                         // 491,520 B
    __hip_bfloat16* G   = (__hip_bfloat16*)(ws + 491520);                // 46,891,008 B
    int*   pos  = (int*)(ws + 491520 + 46891008);                        // 262,144 B
    int*   nsep = (int*)(ws + 491520 + 46891008 + 262144);               // 256 B
    float* PE   = (float*)(ws + 491520 + 46891008 + 262144 + 256);       // 393,216 B
    (void)ws_size; (void)n_in; (void)in_sizes;

    int peBlocks = (S * H_ + 255) / 256;               // 384 for S=128
    setup    <<<120 + peBlocks + B_, 256, 0, stream>>>(W, Wp, PE, peBlocks, S, sep, pos, nsep);
    gemm_ln2 <<<VPAD / MB, 512, 0, stream>>>(emb, g1, b1, Wp, bias, g2, b2, G);
    seg_gather<<<B_ * S, 384, 0, stream>>>(ids, pos, nsep, G, PE, out, S);
}

// Round 21
// 68.020 us; speedup vs baseline: 1.0504x; 1.0504x over previous
//
#include <hip/hip_runtime.h>
#include <hip/hip_bf16.h>

// Shapes (fixed by setup_inputs): B=32, L=2048, V=30522, Dw=300, H=768, S=L/P=128
#define B_   32
#define L_   2048
#define V_   30522
#define DW   300
#define H_   768
#define KP   320              // Dw padded to multiple of 32 for MFMA K
#define NT   (H_/16)          // 48 n-tiles
#define KT   (KP/32)          // 10 k-tiles
#define VPAD 30528            // V rounded up; 30528 = 954 * 32 exactly
#define MB   32               // rows per block (2 m-tiles) -> acc 48 AGPR, 2 blocks/CU
#define NMT  2                // m-tiles per wave
#define NW   6                // n-tiles per wave (8 waves x 6 = 48)
#define APAD 336              // padded LDS row stride (bf16): 672 B rows, 16B-aligned

typedef __attribute__((ext_vector_type(8))) short bf16x8;
typedef __attribute__((ext_vector_type(4))) float f32x4;

// ---------------- K0: fused setup — pack_w | pe_table | sep_scan (blockIdx-ranged) ------------
__global__ void setup(const float* __restrict__ W, __hip_bfloat16* __restrict__ Wp,
                      float* __restrict__ PE, int peBlocks, int S,
                      const int* __restrict__ sep, int* __restrict__ pos,
                      int* __restrict__ nsep) {
    __shared__ int cnt[256];
    int bid = blockIdx.x;
    if (bid < 120) {                                   // ---- pack_w: 120*256 = NT*KT*64
        int t = bid * 256 + threadIdx.x;
        int lane = t & 63;
        int f    = t >> 6;
        int n    = f % NT;
        int kt   = f / NT;
        int col  = n * 16 + (lane & 15);
        int k0   = kt * 32 + (lane >> 4) * 8;
        union { __hip_bfloat16 h[8]; int4 v; } u;
        #pragma unroll
        for (int j = 0; j < 8; ++j) {
            int k = k0 + j;
            float w = (k < DW) ? W[(size_t)k * H_ + col] : 0.f;
            u.h[j] = __float2bfloat16(w);
        }
        reinterpret_cast<int4*>(Wp)[t] = u.v;
    } else if (bid < 120 + peBlocks) {                 // ---- pe_table
        int t = (bid - 120) * 256 + threadIdx.x;
        if (t < S * H_) {
            int s = t / H_, n = t % H_;
            const float cexp = -9.210340371976184f / (float)H_;   // -ln(10000)/H
            float div = expf((float)(2 * (n >> 1)) * cexp);
            float ang = (float)s * div;
            PE[t] = (n & 1) ? cosf(ang) : sinf(ang);
        }
    } else {                                           // ---- sep_scan: one block per batch row
        int b = bid - 120 - peBlocks;
        const int* row = sep + (size_t)b * L_;
        int tid = threadIdx.x;
        int local[8]; int c = 0;
        #pragma unroll
        for (int i = 0; i < 8; ++i) { int v = row[tid * 8 + i]; local[i] = v; c += v; }
        cnt[tid] = c; __syncthreads();
        for (int ofs = 1; ofs < 256; ofs <<= 1) {      // Hillis-Steele inclusive scan
            int v = (tid >= ofs) ? cnt[tid - ofs] : 0;
            __syncthreads();
            cnt[tid] += v;
            __syncthreads();
        }
        int w = cnt[tid] - c;                          // exclusive prefix
        #pragma unroll
        for (int i = 0; i < 8; ++i)
            if (local[i]) { pos[(size_t)b * L_ + w] = tid * 8 + i; ++w; }
        if (tid == 255) nsep[b] = cnt[255];
    }
}

// ---------------- K1: G[v] = LN2(relu(LN1(emb[v]) @ W + b)) — MB=32, 2 blocks/CU --------------
// r16 empirical best (49.6 us, 302 TF fused K=300/N=768 shape), reproduced in r19. Beaten by
// nothing in 9 attempts: MB=64 fused (r15 +2), depth-3 (r11 +3), MB=96 (r18 spill +15),
// coalesced-raw staging (r20 +4), 8-deep pipeline (r7 +15), wider gather (r17 +5.6).
// C/D layout (m89-verified): col = lane&15, row = (lane>>4)*4 + reg.
__global__ void __launch_bounds__(512, 4)
gemm_ln2(const float* __restrict__ emb, const float* __restrict__ g1,
         const float* __restrict__ b1, const __hip_bfloat16* __restrict__ Wp,
         const float* __restrict__ bias, const float* __restrict__ g2,
         const float* __restrict__ b2, __hip_bfloat16* __restrict__ G) {
    __shared__ __hip_bfloat16 sA[MB * APAD];           // 21,504 B
    __shared__ float sred[2][8][MB];                   // 2 KB
    int tid  = threadIdx.x;
    int w    = tid >> 6;
    int lane = tid & 63;
    int r = lane & 15, q = lane >> 4;
    size_t row0 = (size_t)blockIdx.x * MB;

    const bf16x8* Bv = reinterpret_cast<const bf16x8*>(Wp) + (size_t)w * NW * 64 + lane;
    int phase = (int)(blockIdx.x % KT);

    bf16x8 bbuf[2][NW];

    // prologue: issue B loads for kt=phase FIRST (they overlap the LN1 staging)
    {
        const bf16x8* bp = Bv + (size_t)phase * NT * 64;
        #pragma unroll
        for (int nl = 0; nl < NW; ++nl) bbuf[0][nl] = bp[nl * 64];
    }

    // ---- fused LN1 staging: wave w handles rows w*4..w*4+3, in 2 batches of 2 rows ----
    {
        float g1v[5], b1v[5];
        #pragma unroll
        for (int i = 0; i < 5; ++i) {
            int k = lane + i * 64;
            g1v[i] = (k < DW) ? g1[k] : 0.f;
            b1v[i] = (k < DW) ? b1[k] : 0.f;
        }
        bool full = (row0 + MB <= (size_t)V_);         // wave-uniform; false only last block
        if (full) {
            const float* base = emb + (row0 + (size_t)w * 4) * DW;
            #pragma unroll
            for (int batch = 0; batch < 2; ++batch) {
                float xx[2][5];
                #pragma unroll                         // issue 10 loads back-to-back
                for (int rr = 0; rr < 2; ++rr)
                    #pragma unroll
                    for (int i = 0; i < 5; ++i) {
                        int k = lane + i * 64;
                        xx[rr][i] = (k < DW) ? base[(batch * 2 + rr) * DW + k] : 0.f;
                    }
                #pragma unroll                         // 2 independent reduces
                for (int rr = 0; rr < 2; ++rr) {
                    float s = 0.f, ssum = 0.f;
                    #pragma unroll
                    for (int i = 0; i < 5; ++i) { s += xx[rr][i]; ssum += xx[rr][i] * xx[rr][i]; }
                    #pragma unroll
                    for (int m = 32; m >= 1; m >>= 1) { s += __shfl_xor(s, m); ssum += __shfl_xor(ssum, m); }
                    float mu   = s / (float)DW;
                    float var  = ssum / (float)DW - mu * mu;
                    float rstd = rsqrtf(var + 1e-12f);
                    __hip_bfloat16* dst = &sA[(w * 4 + batch * 2 + rr) * APAD];
                    #pragma unroll
                    for (int i = 0; i < 5; ++i) {
                        int k = lane + i * 64;
                        float o = (k < DW) ? (g1v[i] * ((xx[rr][i] - mu) * rstd) + b1v[i]) : 0.f;
                        dst[k] = __float2bfloat16(o);
                    }
                }
            }
        } else {                                       // last block: per-row masked path
            #pragma unroll
            for (int rr = 0; rr < 4; ++rr) {
                int lrow = w * 4 + rr;
                size_t gvr = row0 + lrow;
                __hip_bfloat16* dst = &sA[lrow * APAD];
                if (gvr < V_) {
                    const float* rowp = emb + gvr * (size_t)DW;
                    float x[5]; float s = 0.f, ssum = 0.f;
                    #pragma unroll
                    for (int i = 0; i < 5; ++i) {
                        int k = lane + i * 64;
                        float v = (k < DW) ? rowp[k] : 0.f;
                        x[i] = v; s += v; ssum += v * v;
                    }
                    #pragma unroll
                    for (int m = 32; m >= 1; m >>= 1) { s += __shfl_xor(s, m); ssum += __shfl_xor(ssum, m); }
                    float mu   = s / (float)DW;
                    float var  = ssum / (float)DW - mu * mu;
                    float rstd = rsqrtf(var + 1e-12f);
                    #pragma unroll
                    for (int i = 0; i < 5; ++i) {
                        int k = lane + i * 64;
                        float o = (k < DW) ? (g1v[i] * ((x[i] - mu) * rstd) + b1v[i]) : 0.f;
                        dst[k] = __float2bfloat16(o);
                    }
                } else {
                    for (int k = lane; k < KP; k += 64) dst[k] = __float2bfloat16(0.f);
                }
            }
        }
    }

    f32x4 acc[NW][NMT];
    #pragma unroll
    for (int nl = 0; nl < NW; ++nl)
        #pragma unroll
        for (int m = 0; m < NMT; ++m) acc[nl][m] = (f32x4){0.f, 0.f, 0.f, 0.f};

    const char* sAc = reinterpret_cast<const char*>(sA);
    const int abase = r * (APAD * 2) + q * 16;         // lane's A byte base (m=0, kt=0)

    __syncthreads();                                   // sA ready

    #pragma unroll                                     // FULL unroll: all buf indices static
    for (int i = 0; i < KT; ++i) {
        const int cur = i & 1, nxt = (i + 1) & 1;
        int kt = phase + i; if (kt >= KT) kt -= KT;
        if (i + 1 < KT) {                              // prefetch kt+1's B (global)
            int ktn = phase + i + 1; if (ktn >= KT) ktn -= KT;
            const bf16x8* bp = Bv + (size_t)ktn * NT * 64;
            #pragma unroll
            for (int nl = 0; nl < NW; ++nl) bbuf[nxt][nl] = bp[nl * 64];
        }
        __builtin_amdgcn_sched_barrier(0);             // prefetch may NOT sink below MFMAs
        // A direct from LDS (compiler emits counted lgkmcnt; saves abuf regs)
        bf16x8 a0 = *reinterpret_cast<const bf16x8*>(sAc + abase + kt * 64);
        bf16x8 a1 = *reinterpret_cast<const bf16x8*>(sAc + abase + 16 * APAD * 2 + kt * 64);
        __builtin_amdgcn_s_setprio(1);                 // T5: favor MFMA wave
        #pragma unroll
        for (int nl = 0; nl < NW; ++nl) {
            acc[nl][0] = __builtin_amdgcn_mfma_f32_16x16x32_bf16(a0, bbuf[cur][nl], acc[nl][0], 0, 0, 0);
            acc[nl][1] = __builtin_amdgcn_mfma_f32_16x16x32_bf16(a1, bbuf[cur][nl], acc[nl][1], 0, 0, 0);
        }
        __builtin_amdgcn_s_setprio(0);
    }

    // bias + relu + in-wave partial stats (over this wave's 96 cols)
    float s_[NMT][4], ss_[NMT][4];
    #pragma unroll
    for (int m = 0; m < NMT; ++m)
        #pragma unroll
        for (int j = 0; j < 4; ++j) { s_[m][j] = 0.f; ss_[m][j] = 0.f; }
    #pragma unroll
    for (int nl = 0; nl < NW; ++nl) {
        float bn = bias[w * 96 + nl * 16 + r];
        #pragma unroll
        for (int m = 0; m < NMT; ++m)
            #pragma unroll
            for (int j = 0; j < 4; ++j) {
                float v = acc[nl][m][j] + bn;
                v = v > 0.f ? v : 0.f;
                acc[nl][m][j] = v;
                s_[m][j] += v; ss_[m][j] += v * v;
            }
    }
    #pragma unroll
    for (int msk = 1; msk < 16; msk <<= 1)             // reduce across the 16 r-lanes
        #pragma unroll
        for (int m = 0; m < NMT; ++m)
            #pragma unroll
            for (int j = 0; j < 4; ++j) {
                s_[m][j]  += __shfl_xor(s_[m][j],  msk);
                ss_[m][j] += __shfl_xor(ss_[m][j], msk);
            }
    if (r == 0) {                                      // publish wave partials
        #pragma unroll
        for (int m = 0; m < NMT; ++m)
            #pragma unroll
            for (int j = 0; j < 4; ++j) {
                int row = m * 16 + q * 4 + j;
                sred[0][w][row] = s_[m][j];
                sred[1][w][row] = ss_[m][j];
            }
    }
    __syncthreads();

    #pragma unroll
    for (int m = 0; m < NMT; ++m) {
        #pragma unroll
        for (int j = 0; j < 4; ++j) {
            int row = m * 16 + q * 4 + j;
            float ts = 0.f, tss = 0.f;
            #pragma unroll
            for (int ww = 0; ww < 8; ++ww) { ts += sred[0][ww][row]; tss += sred[1][ww][row]; }
            float mu   = ts / (float)H_;
            float var  = tss / (float)H_ - mu * mu;
            float rstd = rsqrtf(var + 1e-12f);
            s_[m][j]  = mu;                            // reuse as mu
            ss_[m][j] = rstd;                          // reuse as rstd
        }
    }
    #pragma unroll
    for (int nl = 0; nl < NW; ++nl) {
        int col = w * 96 + nl * 16 + r;
        float gg = g2[col], bb = b2[col];
        #pragma unroll
        for (int m = 0; m < NMT; ++m)
            #pragma unroll
            for (int j = 0; j < 4; ++j) {
                size_t rowg = row0 + m * 16 + q * 4 + j;
                float val = gg * (acc[nl][m][j] - s_[m][j]) * ss_[m][j] + bb;
                G[rowg * H_ + col] = __float2bfloat16(val);
            }
    }
}

// ---------------- K2: out[b,s,:] = mean_{t in seg(b,s)} G[ids[b,t]] + PE[s] -------------------
// r16's best version: 384 thr = 4 groups x 96 lanes (r17's 768-thr regressed +5.6 us).
__global__ void seg_gather(const int* __restrict__ ids, const int* __restrict__ pos,
                           const int* __restrict__ nsep, const __hip_bfloat16* __restrict__ G,
                           const float* __restrict__ PE, float* __restrict__ out, int S) {
    int blk = blockIdx.x;
    int s = blk % S, b = blk / S;
    int tid = threadIdx.x;
    int g = tid / 96;
    int l = tid % 96;
    int ns = nsep[b];
    int lo, hi;
    if (s > ns) { lo = 1; hi = 0; }                    // empty segment
    else {
        lo = (s == 0) ? 0 : pos[(size_t)b * L_ + (s - 1)] + 1;
        hi = (s < ns) ? pos[(size_t)b * L_ + s] - 1 : L_ - 1;   // s==ns: tail after last sep
    }
    int cnt = hi - lo + 1; if (cnt < 0) cnt = 0;

    float a[8] = {0.f, 0.f, 0.f, 0.f, 0.f, 0.f, 0.f, 0.f};
    for (int t = lo + g; t <= hi; t += 4) {
        int v = ids[(size_t)b * L_ + t];
        int4 raw = *reinterpret_cast<const int4*>(G + (size_t)v * H_ + l * 8);
        const unsigned short* u = reinterpret_cast<const unsigned short*>(&raw);
        #pragma unroll
        for (int k = 0; k < 8; ++k) {
            union { unsigned int i; float f; } c; c.i = ((unsigned int)u[k]) << 16;
            a[k] += c.f;
        }
    }
    __shared__ float red[3][96 * 8];                   // 9 KB
    if (g > 0) {
        #pragma unroll
        for (int k = 0; k < 8; ++k) red[g - 1][l * 8 + k] = a[k];
    }
    __syncthreads();
    if (g == 0) {
        float inv = (cnt > 0) ? 1.f / (float)cnt : 0.f;
        float* orow = out + ((size_t)b * S + s) * H_;
        const float* pe = PE + (size_t)s * H_;
        #pragma unroll
        for (int k = 0; k < 8; ++k) {
            int n = l * 8 + k;
            float tot = a[k] + red[0][l * 8 + k] + red[1][l * 8 + k] + red[2][l * 8 + k];
            orow[n] = tot * inv + pe[n];
        }
    }
}

// ---------------- host launcher ----------------
extern "C" void kernel_launch(void* const* d_in, const int* in_sizes, int n_in,
                              void* d_out, int out_size, void* d_ws, size_t ws_size,
                              hipStream_t stream) {
    const int*   ids  = (const int*)d_in[0];
    const int*   sep  = (const int*)d_in[1];
    const float* emb  = (const float*)d_in[3];
    const float* g1   = (const float*)d_in[4];
    const float* b1   = (const float*)d_in[5];
    const float* W    = (const float*)d_in[6];
    const float* bias = (const float*)d_in[7];
    const float* g2   = (const float*)d_in[8];
    const float* b2   = (const float*)d_in[9];
    float* out = (float*)d_out;

    int S = out_size / (B_ * H_);                      // 128

    // workspace layout (all offsets 16B-aligned)
    char* ws = (char*)d_ws;
    __hip_bfloat16* Wp  = (__hip_bfloat16*)(ws);                         // 491,520 B
    __hip_bfloat16* G   = (__hip_bfloat16*)(ws + 491520);                // 46,891,008 B
    int*   pos  = (int*)(ws + 491520 + 46891008);                        // 262,144 B
    int*   nsep = (int*)(ws + 491520 + 46891008 + 262144);               // 256 B
    float* PE   = (float*)(ws + 491520 + 46891008 + 262144 + 256);       // 393,216 B
    (void)ws_size; (void)n_in; (void)in_sizes;

    int peBlocks = (S * H_ + 255) / 256;               // 384 for S=128
    setup    <<<120 + peBlocks + B_, 256, 0, stream>>>(W, Wp, PE, peBlocks, S, sep, pos, nsep);
    gemm_ln2 <<<VPAD / MB, 512, 0, stream>>>(emb, g1, b1, Wp, bias, g2, b2, G);
    seg_gather<<<B_ * S, 384, 0, stream>>>(ids, pos, nsep, G, PE, out, S);
}